// Round 3
// baseline (470.302 us; speedup 1.0000x reference)
//
#include <hip/hip_runtime.h>
#include <stdint.h>

typedef unsigned int uint;
typedef unsigned short ushort;
typedef unsigned char uchar;
typedef __attribute__((ext_vector_type(8))) short bf16x8;
typedef __attribute__((ext_vector_type(4))) float f32x4;

__device__ __forceinline__ ushort f2bf(float f) {
  uint u = __builtin_bit_cast(uint, f);
  return (ushort)((u + 0x7FFFu + ((u >> 16) & 1u)) >> 16);
}

// ---------------------------------------------------------------------------
// Mask element width: esz word stays nonzero (0x01010101 from memset) if every
// sampled 4-byte word is in {0,1,0x3F800000} (int32/float32 masks); byte masks
// produce other patterns (e.g. 0x00010000) with certainty over 48K samples.
__global__ __launch_bounds__(256) void k_detect(
    const uint* __restrict__ mp, const uint* __restrict__ ms,
    const uint* __restrict__ mt, int* __restrict__ esz) {
  int bid = blockIdx.x;                 // 192 blocks: 3 masks x 64 chunks
  const uint* m = (bid < 64) ? mp : (bid < 128) ? ms : mt;
  uint v = m[(size_t)(bid & 63) * 65521 + threadIdx.x];
  if (!(v == 0u || v == 1u || v == 0x3F800000u)) atomicAnd(esz, 0);
}

// ---------------------------------------------------------------------------
// Fused-weight stage 1: T1 = W_space @ W_mix[0:128], T2 = W_same @ W_mix[128:256]
__global__ __launch_bounds__(256) void k_fuse1(
    const float* __restrict__ Ws, const float* __restrict__ Wsame,
    const float* __restrict__ Wm, float* __restrict__ T1, float* __restrict__ T2) {
  int idx = blockIdx.x * 256 + threadIdx.x;
  if (idx >= 81920) return;
  int r = idx >> 7, n = idx & 127;
  float s = 0.f;
  if (r < 384) {
    for (int c = 0; c < 128; ++c) s += Ws[r * 128 + c] * Wm[c * 128 + n];
    T1[r * 128 + n] = s;
  } else {
    int rr = r - 384;
    for (int c = 0; c < 128; ++c) s += Wsame[rr * 128 + c] * Wm[(128 + c) * 128 + n];
    T2[rr * 128 + n] = s;
  }
}

// ---------------------------------------------------------------------------
// Stage 2: UT[y][n][k] (bf16, [n][k] layout) for y=0:origin 1:pred 2:succ
// 3:same, plus bias vectors cvec[0..3][n] (c0 includes all constant paths).
__global__ __launch_bounds__(256) void k_fuse2(
    const float* __restrict__ We, const float* __restrict__ be,
    const float* __restrict__ bs, const float* __restrict__ bsame,
    const float* __restrict__ bm, const float* __restrict__ Wm,
    const float* __restrict__ T1, const float* __restrict__ T2,
    ushort* __restrict__ UT, float* __restrict__ cvec) {
  int idx = blockIdx.x * 256 + threadIdx.x;
  if (idx < 65536) {
    int y = idx >> 14, n = (idx >> 7) & 127, k = idx & 127;
    float s = 0.f;
    if (y == 0)
      for (int m = 0; m < 128; ++m)
        s += We[k * 512 + m] * (T1[(128 + m) * 128 + n] + T2[m * 128 + n]);
    else if (y == 1)
      for (int m = 0; m < 128; ++m) s += We[k * 512 + 128 + m] * T1[m * 128 + n];
    else if (y == 2)
      for (int m = 0; m < 128; ++m) s += We[k * 512 + 256 + m] * T1[(256 + m) * 128 + n];
    else
      for (int m = 0; m < 128; ++m) s += We[k * 512 + 384 + m] * T2[(128 + m) * 128 + n];
    UT[((size_t)y * 128 + n) * 128 + k] = f2bf(s);
  } else if (idx < 66048) {
    int cid = idx - 65536, cv = cid >> 7, n = cid & 127;
    float s = 0.f;
    if (cv == 0) {
      for (int m = 0; m < 128; ++m)
        s += be[m] * (T1[(128 + m) * 128 + n] + T2[m * 128 + n]);
      for (int c = 0; c < 128; ++c) s += bs[c] * Wm[c * 128 + n];
      for (int c = 0; c < 128; ++c) s += bsame[c] * Wm[(128 + c) * 128 + n];
      s += bm[n];
    } else if (cv == 1) {
      for (int m = 0; m < 128; ++m) s += be[128 + m] * T1[m * 128 + n];
    } else if (cv == 2) {
      for (int m = 0; m < 128; ++m) s += be[256 + m] * T1[(256 + m) * 128 + n];
    } else {
      for (int m = 0; m < 128; ++m) s += be[384 + m] * T2[(128 + m) * 128 + n];
    }
    cvec[cv * 128 + n] = s;
  }
}

// ---------------------------------------------------------------------------
// Encoder: feat(f32) @ UT[y].  y=0 -> out += c0 (f32, final-output base);
// y=1..3 -> e'_mid written in MFMA-B-FRAGMENT order via LDS transpose:
//   tile(b,kb) of 8192 ushorts; off = ((j2*2+kc)*4+quad)*128 + lr*8 + e,
//   where k-row local rl = kc*32+quad*8+e, feature n = j2*16+lr.
__global__ __launch_bounds__(256) void k_enc(
    const float* __restrict__ feat, const ushort* __restrict__ UT,
    const float* __restrict__ cvec, float* __restrict__ out,
    ushort* __restrict__ eT0, ushort* __restrict__ eT1, ushort* __restrict__ eT2) {
  __shared__ ushort As[64 * 72];
  __shared__ ushort Bs[128 * 72];
  __shared__ ushort stage[8192];
  const int t = threadIdx.x;
  const int gm0 = blockIdx.x * 64;
  const int y = blockIdx.y;
  const int lane = t & 63, wave = t >> 6;
  const int m0w = (wave >> 1) * 32, n0w = (wave & 1) * 64;
  const int quad = lane >> 4, lr = lane & 15;
  const int am = t >> 2, aq = t & 3;
  const int bn = t >> 1, bh = t & 1;
  f32x4 acc[2][4] = {};
  for (int k0 = 0; k0 < 128; k0 += 64) {
    const float* asrc = feat + (size_t)(gm0 + am) * 128 + k0 + aq * 16;
    float4 f0 = *(const float4*)asrc;
    float4 f1 = *(const float4*)(asrc + 4);
    float4 f2 = *(const float4*)(asrc + 8);
    float4 f3 = *(const float4*)(asrc + 12);
    ushort h[16];
    h[0] = f2bf(f0.x); h[1] = f2bf(f0.y); h[2] = f2bf(f0.z); h[3] = f2bf(f0.w);
    h[4] = f2bf(f1.x); h[5] = f2bf(f1.y); h[6] = f2bf(f1.z); h[7] = f2bf(f1.w);
    h[8] = f2bf(f2.x); h[9] = f2bf(f2.y); h[10] = f2bf(f2.z); h[11] = f2bf(f2.w);
    h[12] = f2bf(f3.x); h[13] = f2bf(f3.y); h[14] = f2bf(f3.z); h[15] = f2bf(f3.w);
    const ushort* bsrc = UT + ((size_t)y * 128 + bn) * 128 + k0 + bh * 32;
    bf16x8 bv0 = *(const bf16x8*)bsrc;
    bf16x8 bv1 = *(const bf16x8*)(bsrc + 8);
    bf16x8 bv2 = *(const bf16x8*)(bsrc + 16);
    bf16x8 bv3 = *(const bf16x8*)(bsrc + 24);
    *(bf16x8*)&As[am * 72 + aq * 16] = *(bf16x8*)&h[0];
    *(bf16x8*)&As[am * 72 + aq * 16 + 8] = *(bf16x8*)&h[8];
    *(bf16x8*)&Bs[bn * 72 + bh * 32] = bv0;
    *(bf16x8*)&Bs[bn * 72 + bh * 32 + 8] = bv1;
    *(bf16x8*)&Bs[bn * 72 + bh * 32 + 16] = bv2;
    *(bf16x8*)&Bs[bn * 72 + bh * 32 + 24] = bv3;
    __syncthreads();
#pragma unroll
    for (int kc = 0; kc < 2; ++kc) {
      bf16x8 a[2], b[4];
#pragma unroll
      for (int i = 0; i < 2; ++i)
        a[i] = *(const bf16x8*)&As[(m0w + i * 16 + lr) * 72 + kc * 32 + quad * 8];
#pragma unroll
      for (int j = 0; j < 4; ++j)
        b[j] = *(const bf16x8*)&Bs[(n0w + j * 16 + lr) * 72 + kc * 32 + quad * 8];
#pragma unroll
      for (int i = 0; i < 2; ++i)
#pragma unroll
        for (int j = 0; j < 4; ++j)
          acc[i][j] = __builtin_amdgcn_mfma_f32_16x16x32_bf16(a[i], b[j], acc[i][j], 0, 0, 0);
    }
    __syncthreads();
  }
  if (y == 0) {
#pragma unroll
    for (int i = 0; i < 2; ++i)
#pragma unroll
      for (int j = 0; j < 4; ++j)
#pragma unroll
        for (int r = 0; r < 4; ++r) {
          int m = gm0 + m0w + i * 16 + quad * 4 + r;
          int n = n0w + j * 16 + lr;
          out[(size_t)m * 128 + n] = acc[i][j][r] + cvec[n];
        }
  } else {
#pragma unroll
    for (int i = 0; i < 2; ++i)
#pragma unroll
      for (int j = 0; j < 4; ++j)
#pragma unroll
        for (int r = 0; r < 4; ++r) {
          int rl = m0w + i * 16 + quad * 4 + r;
          int n = n0w + j * 16 + lr;
          int kc = rl >> 5, qd = (rl >> 3) & 3, e = rl & 7;
          stage[((((n >> 4) * 2 + kc) * 4 + qd) * 16 + (n & 15)) * 8 + e] =
              f2bf(acc[i][j][r]);
        }
    __syncthreads();
    ushort* eT = (y == 1) ? eT0 : (y == 2) ? eT1 : eT2;
    ushort* dst = eT + ((size_t)(gm0 >> 11) * 32 + ((gm0 >> 6) & 31)) * 8192 + t * 32;
    const ushort* src = stage + t * 32;
#pragma unroll
    for (int p = 0; p < 4; ++p)
      *(bf16x8*)(dst + p * 8) = *(const bf16x8*)(src + p * 8);
  }
}

// ---------------------------------------------------------------------------
// Masked-mean GEMMs, barrier-free K-loop: mask A-fragments and frag-ordered
// e' B-fragments loaded direct to registers with 1-iter ping-pong prefetch.
// Fused degree count; epilogue atomicAdds acc/deg + ind*c_mid into out.
__global__ __launch_bounds__(256, 3) void k_mm(
    const void* __restrict__ mp, const void* __restrict__ ms,
    const void* __restrict__ mt, const ushort* __restrict__ eT0,
    const ushort* __restrict__ eT1, const ushort* __restrict__ eT2,
    const float* __restrict__ cvec, float* __restrict__ out,
    const int* __restrict__ esz_p) {
  __shared__ uint degs[64];
  const int t = threadIdx.x;
  // XCD-aware swizzle: id%8 = XCD; each (b,mid) slab stays on one XCD.
  const int id = blockIdx.x;
  const int xcd = id & 7, q = id >> 3;
  const int mtile = q & 31, gg = xcd * 3 + (q >> 5);
  const int b = gg & 7, mid = gg >> 3;
  const void* mask = (mid == 0) ? mp : (mid == 1) ? ms : mt;
  const ushort* eT = (mid == 0) ? eT0 : (mid == 1) ? eT1 : eT2;
  const float* cm = cvec + (mid + 1) * 128;
  const bool is4 = (*esz_p != 0);
  if (t < 64) degs[t] = 0;
  __syncthreads();

  const int lane = t & 63, wave = t >> 6;
  const int m0w = (wave >> 1) * 32, n0w = (wave & 1) * 64;
  const int quad = lane >> 4, lr = lane & 15;
  const int jb = n0w >> 4;
  const size_t rowbase = (size_t)b * 2048 + mtile * 64;
  const size_t r0 = rowbase + m0w + lr;       // A row, i=0
  const size_t r1 = r0 + 16;                  // A row, i=1
  const uint* A40 = (const uint*)mask + r0 * 2048 + quad * 8;
  const uint* A41 = (const uint*)mask + r1 * 2048 + quad * 8;
  const uchar* A10 = (const uchar*)mask + r0 * 2048 + quad * 8;
  const uchar* A11 = (const uchar*)mask + r1 * 2048 + quad * 8;
  const ushort* bbase = eT + (size_t)b * 32 * 8192 + quad * 128 + lr * 8;

  f32x4 acc[2][4] = {};
  uint4 pa[2][2][2];
  uint2 pa8[2][2];
  bf16x8 pb[2][4];
  int cnt0 = 0, cnt1 = 0;

#define LOAD_ITER(IT, BUF)                                                   \
  do {                                                                       \
    int it_ = (IT);                                                          \
    if (is4) {                                                               \
      const uint* p0_ = A40 + it_ * 32;                                      \
      const uint* p1_ = A41 + it_ * 32;                                      \
      pa[BUF][0][0] = *(const uint4*)p0_;                                    \
      pa[BUF][0][1] = *(const uint4*)(p0_ + 4);                              \
      pa[BUF][1][0] = *(const uint4*)p1_;                                    \
      pa[BUF][1][1] = *(const uint4*)(p1_ + 4);                              \
    } else {                                                                 \
      pa8[BUF][0] = *(const uint2*)(A10 + it_ * 32);                         \
      pa8[BUF][1] = *(const uint2*)(A11 + it_ * 32);                         \
    }                                                                        \
    const ushort* bp_ = bbase + (it_ >> 1) * 8192 + (it_ & 1) * 512;         \
    _Pragma("unroll")                                                        \
    for (int j_ = 0; j_ < 4; ++j_)                                           \
      pb[BUF][j_] = *(const bf16x8*)(bp_ + (jb + j_) * 1024);                \
  } while (0)

  LOAD_ITER(0, 0);
#pragma unroll 2
  for (int it = 0; it < 64; ++it) {
    const int cur = it & 1;
    if (it < 63) LOAD_ITER(it + 1, cur ^ 1);
    union { bf16x8 v; uint u[4]; } af[2];
    if (is4) {
#pragma unroll
      for (int i = 0; i < 2; ++i) {
        uint x[8] = {pa[cur][i][0].x, pa[cur][i][0].y, pa[cur][i][0].z,
                     pa[cur][i][0].w, pa[cur][i][1].x, pa[cur][i][1].y,
                     pa[cur][i][1].z, pa[cur][i][1].w};
        int c = 0;
#pragma unroll
        for (int p = 0; p < 4; ++p) {
          af[i].u[p] = (x[2 * p] ? 0x3F80u : 0u) | (x[2 * p + 1] ? 0x3F800000u : 0u);
          c += (x[2 * p] != 0u) + (x[2 * p + 1] != 0u);
        }
        if (i == 0) cnt0 += c; else cnt1 += c;
      }
    } else {
#pragma unroll
      for (int i = 0; i < 2; ++i) {
        uint wl = pa8[cur][i].x, wh = pa8[cur][i].y;
        int c = 0;
        af[i].u[0] = ((wl & 0xFFu) ? 0x3F80u : 0u) | ((wl & 0xFF00u) ? 0x3F800000u : 0u);
        af[i].u[1] = ((wl & 0xFF0000u) ? 0x3F80u : 0u) | ((wl & 0xFF000000u) ? 0x3F800000u : 0u);
        af[i].u[2] = ((wh & 0xFFu) ? 0x3F80u : 0u) | ((wh & 0xFF00u) ? 0x3F800000u : 0u);
        af[i].u[3] = ((wh & 0xFF0000u) ? 0x3F80u : 0u) | ((wh & 0xFF000000u) ? 0x3F800000u : 0u);
        c += ((wl & 0xFFu) != 0u) + ((wl & 0xFF00u) != 0u) +
             ((wl & 0xFF0000u) != 0u) + ((wl & 0xFF000000u) != 0u) +
             ((wh & 0xFFu) != 0u) + ((wh & 0xFF00u) != 0u) +
             ((wh & 0xFF0000u) != 0u) + ((wh & 0xFF000000u) != 0u);
        if (i == 0) cnt0 += c; else cnt1 += c;
      }
    }
#pragma unroll
    for (int i = 0; i < 2; ++i)
#pragma unroll
      for (int j = 0; j < 4; ++j)
        acc[i][j] = __builtin_amdgcn_mfma_f32_16x16x32_bf16(af[i].v, pb[cur][j], acc[i][j], 0, 0, 0);
  }
#undef LOAD_ITER

  // Degrees: only n0w==0 waves contribute (each (row,k) counted exactly once).
  if ((wave & 1) == 0) {
    atomicAdd(&degs[m0w + lr], (uint)cnt0);
    atomicAdd(&degs[m0w + 16 + lr], (uint)cnt1);
  }
  __syncthreads();

#pragma unroll
  for (int i = 0; i < 2; ++i)
#pragma unroll
    for (int r = 0; r < 4; ++r) {
      int ml = m0w + i * 16 + quad * 4 + r;
      uint d = degs[ml];
      float inv = 1.0f / (float)(d > 0u ? d : 1u);
      float ind = (d > 0u) ? 1.0f : 0.0f;
#pragma unroll
      for (int j = 0; j < 4; ++j) {
        int n = n0w + j * 16 + lr;
        atomicAdd(&out[(rowbase + ml) * 128 + n], acc[i][j][r] * inv + ind * cm[n]);
      }
    }
}

// ---------------------------------------------------------------------------
extern "C" void kernel_launch(void* const* d_in, const int* in_sizes, int n_in,
                              void* d_out, int out_size, void* d_ws,
                              size_t ws_size, hipStream_t stream) {
  const float* features = (const float*)d_in[0];
  const void* pred = d_in[1];
  const void* succ = d_in[2];
  const void* same = d_in[3];
  const float* W_enc = (const float*)d_in[4];
  const float* b_enc = (const float*)d_in[5];
  const float* W_space = (const float*)d_in[6];
  const float* b_space = (const float*)d_in[7];
  const float* W_same = (const float*)d_in[8];
  const float* b_same = (const float*)d_in[9];
  const float* W_mix = (const float*)d_in[10];
  const float* b_mix = (const float*)d_in[11];
  float* out = (float*)d_out;

  char* wsb = (char*)d_ws;
  ushort* UT = (ushort*)wsb;                       // 4*128*128 bf16 = 128 KB
  float* cvec = (float*)(wsb + 131072);            // 4*128 f32
  float* T1 = (float*)(wsb + 133120);              // 384*128 f32
  float* T2 = (float*)(wsb + 329728);              // 256*128 f32
  ushort* eT0 = (ushort*)(wsb + 460800);           // 16384*128 bf16 (frag order)
  ushort* eT1 = (ushort*)(wsb + 460800 + 4194304);
  ushort* eT2 = (ushort*)(wsb + 460800 + 8388608);
  int* esz = (int*)(wsb + 460800 + 12582912);

  hipMemsetAsync(esz, 1, 4, stream);  // nonzero = 4-byte elements
  k_detect<<<192, 256, 0, stream>>>((const uint*)pred, (const uint*)succ,
                                    (const uint*)same, esz);
  k_fuse1<<<320, 256, 0, stream>>>(W_space, W_same, W_mix, T1, T2);
  k_fuse2<<<258, 256, 0, stream>>>(W_enc, b_enc, b_space, b_same, b_mix, W_mix,
                                   T1, T2, UT, cvec);
  k_enc<<<dim3(256, 4), 256, 0, stream>>>(features, UT, cvec, out, eT0, eT1, eT2);
  k_mm<<<768, 256, 0, stream>>>(pred, succ, same, eT0, eT1, eT2, cvec, out, esz);
}